// Round 1
// baseline (793.895 us; speedup 1.0000x reference)
//
#include <hip/hip_runtime.h>

// Problem constants (from reference)
#define E_EDGES 131072
#define K_NB    10
#define D_DIM   128
#define U_DIM   32
#define A_DIM   16
#define R_DIM   4

// Kernel tiling
#define EPG     4                    // edge-sides per wave pass
#define WAVES   8                    // waves per block
#define BLOCK   (WAVES * 64)
#define NGROUPS ((2 * E_EDGES) / EPG)   // 65536 wave-groups
#define NBLOCKS (NGROUPS / WAVES)       // 8192 blocks

__global__ __launch_bounds__(BLOCK, 2)
void gatne_fused(const int*   __restrict__ edge_index,  // [2,E]
                 const float* __restrict__ edge_attr,   // [E,R]
                 const int*   __restrict__ nbr,         // [2,E,K]
                 const float* __restrict__ emb,         // [N,D]
                 const float* __restrict__ u,           // [N,R,U] (=[N,128])
                 const float* __restrict__ Wt,          // [R,U,A]
                 const float* __restrict__ wt,          // [R,A]
                 const float* __restrict__ Mt,          // [R,U,D] (=[128,128])
                 float*       __restrict__ out)         // [2,E,D]
{
    __shared__ float M_lds[R_DIM * U_DIM * D_DIM];      // 64 KB
    __shared__ float ur_lds[WAVES][D_DIM];              // 4 KB  (per-wave u_r)
    __shared__ float coef_lds[WAVES][EPG][D_DIM];       // 16 KB (per-wave coef)

    const int tid = threadIdx.x;

    // ---- stage M into LDS (linear copy, one barrier for the whole kernel) ----
    #pragma unroll
    for (int j = 0; j < (R_DIM * U_DIM * D_DIM) / (BLOCK * 4); ++j) {
        const int o = (j * BLOCK + tid) * 4;
        *reinterpret_cast<float4*>(&M_lds[o]) =
            *reinterpret_cast<const float4*>(&Mt[o]);
    }
    __syncthreads();

    const int wave = tid >> 6;
    const int lane = tid & 63;
    const int grp  = blockIdx.x * WAVES + wave;   // one group of EPG edge-sides
    const int es0  = grp * EPG;                   // first edge-side id
    const int side = es0 / E_EDGES;               // uniform within group
    const int i0   = es0 - side * E_EDGES;        // edge id of first

    // lane -> (r'=rl, a=al) mapping for the attention score phase
    const int rl = lane >> 4;
    const int al = lane & 15;

    // register-cache this lane's W column: W[rl, :, al]  (32 regs, constant)
    float Wreg[U_DIM];
    #pragma unroll
    for (int uu = 0; uu < U_DIM; ++uu)
        Wreg[uu] = Wt[(rl * U_DIM + uu) * A_DIM + al];
    const float wreg0 = wt[0 * A_DIM + al];
    const float wreg1 = wt[1 * A_DIM + al];
    const float wreg2 = wt[2 * A_DIM + al];
    const float wreg3 = wt[3 * A_DIM + al];

    // cooperative index / attr loads (broadcast later via shfl/readlane)
    int idxA = 0;
    if (lane < EPG * K_NB) idxA = nbr[es0 * K_NB + lane];          // 40 ints
    int entv = 0;
    if (lane < EPG)        entv = edge_index[es0 + lane];          // 4 ints
    float attrv = 0.f;
    if (lane < EPG * R_DIM) attrv = edge_attr[i0 * R_DIM + lane];  // 16 floats

    float* urp = ur_lds[wave];
    float* cfp = &coef_lds[wave][0][0];

    float2 b2[EPG];

    // ---------------- per-edge phase: gather, attention, coef ----------------
    #pragma unroll
    for (int e = 0; e < EPG; ++e) {
        const float at0 = __shfl(attrv, e * 4 + 0);
        const float at1 = __shfl(attrv, e * 4 + 1);
        const float at2 = __shfl(attrv, e * 4 + 2);
        const float at3 = __shfl(attrv, e * 4 + 3);
        const int   ent = __shfl(entv, e);
        // this lane's attr[rl] (rl == (2*lane)>>5 too, reused for coef)
        const float atm = (rl == 0) ? at0 : (rl == 1) ? at1 : (rl == 2) ? at2 : at3;

        // gather K neighbors' u rows (each lane: float2 of the 128-float row)
        float2 vals[K_NB];
        #pragma unroll
        for (int k = 0; k < K_NB; ++k) {
            const int node = __shfl(idxA, e * K_NB + k);   // uniform -> readlane
            vals[k] = *reinterpret_cast<const float2*>(&u[node * D_DIM + 2 * lane]);
        }
        b2[e] = *reinterpret_cast<const float2*>(&emb[ent * D_DIM + 2 * lane]);

        float sx = 0.f, sy = 0.f;
        #pragma unroll
        for (int k = 0; k < K_NB; ++k) { sx += vals[k].x; sy += vals[k].y; }
        sx *= 0.1f; sy *= 0.1f;                 // mean over K=10
        *reinterpret_cast<float2*>(&urp[2 * lane]) = make_float2(sx, sy);
        // wave-private LDS: in-order DS pipe makes this visible to all lanes
        // without a barrier (single-wave producer/consumer).

        // w_r[al] = sum_r' attr[r'] * w[r',al]
        const float wr = at0 * wreg0 + at1 * wreg1 + at2 * wreg2 + at3 * wreg3;

        // scores: g[r] = sum_u u_r[r,u] * W[rl,u,al];  h[r,al] = sum_rl attr*g
        float sc[R_DIM];
        #pragma unroll
        for (int r = 0; r < R_DIM; ++r) {
            float g = 0.f;
            #pragma unroll
            for (int u4 = 0; u4 < U_DIM / 4; ++u4) {
                const float4 uv =
                    *reinterpret_cast<const float4*>(&urp[r * U_DIM + u4 * 4]);
                g += uv.x * Wreg[u4 * 4 + 0];
                g += uv.y * Wreg[u4 * 4 + 1];
                g += uv.z * Wreg[u4 * 4 + 2];
                g += uv.w * Wreg[u4 * 4 + 3];
            }
            float v0 = atm * g;
            v0 += __shfl_xor(v0, 16);           // reduce over r' groups
            v0 += __shfl_xor(v0, 32);
            float t = tanhf(v0) * wr;           // tanh(h[r,al]) * w_r[al]
            t += __shfl_xor(t, 1);              // reduce over a
            t += __shfl_xor(t, 2);
            t += __shfl_xor(t, 4);
            t += __shfl_xor(t, 8);
            sc[r] = t;                          // score[r], replicated all lanes
        }

        // softmax over R=4 (replicated per-lane, trivial)
        const float mx  = fmaxf(fmaxf(sc[0], sc[1]), fmaxf(sc[2], sc[3]));
        const float ex0 = expf(sc[0] - mx), ex1 = expf(sc[1] - mx);
        const float ex2 = expf(sc[2] - mx), ex3 = expf(sc[3] - mx);
        const float inv = 1.f / (ex0 + ex1 + ex2 + ex3);
        const float a0 = ex0 * inv, a1 = ex1 * inv, a2 = ex2 * inv, a3 = ex3 * inv;

        // coef[ru] = attr[r] * v[u], v[u] = sum_r att[r]*u_r[r,u]
        // lane owns ru = 2*lane, 2*lane+1  (r = lane>>4 = rl)
        const int ub = (2 * lane) & 31;
        const float vA = a0 * urp[0 * U_DIM + ub]     + a1 * urp[1 * U_DIM + ub] +
                         a2 * urp[2 * U_DIM + ub]     + a3 * urp[3 * U_DIM + ub];
        const float vB = a0 * urp[0 * U_DIM + ub + 1] + a1 * urp[1 * U_DIM + ub + 1] +
                         a2 * urp[2 * U_DIM + ub + 1] + a3 * urp[3 * U_DIM + ub + 1];
        *reinterpret_cast<float2*>(&cfp[e * D_DIM + 2 * lane]) =
            make_float2(atm * vA, atm * vB);
    }

    // ---------------- joint matvec: out_d = sum_ru coef[ru] * M[ru,d] --------
    float2 acc[EPG];
    #pragma unroll
    for (int e = 0; e < EPG; ++e) { acc[e].x = 0.f; acc[e].y = 0.f; }

    for (int c = 0; c < (R_DIM * U_DIM) / 4; ++c) {    // 32 chunks of 4 ru
        float4 cf4[EPG];                               // uniform (broadcast) reads
        #pragma unroll
        for (int e = 0; e < EPG; ++e)
            cf4[e] = *reinterpret_cast<const float4*>(&cfp[e * D_DIM + c * 4]);
        #pragma unroll
        for (int jj = 0; jj < 4; ++jj) {
            const float2 m2 = *reinterpret_cast<const float2*>(
                &M_lds[(c * 4 + jj) * D_DIM + 2 * lane]);
            #pragma unroll
            for (int e = 0; e < EPG; ++e) {
                const float cv = (jj == 0) ? cf4[e].x : (jj == 1) ? cf4[e].y
                               : (jj == 2) ? cf4[e].z : cf4[e].w;
                acc[e].x += cv * m2.x;
                acc[e].y += cv * m2.y;
            }
        }
    }

    // ---------------- epilogue: + emb, L2 normalize, store -------------------
    #pragma unroll
    for (int e = 0; e < EPG; ++e) {
        const float ox = b2[e].x + acc[e].x;
        const float oy = b2[e].y + acc[e].y;
        float ss = ox * ox + oy * oy;
        ss += __shfl_xor(ss, 1);
        ss += __shfl_xor(ss, 2);
        ss += __shfl_xor(ss, 4);
        ss += __shfl_xor(ss, 8);
        ss += __shfl_xor(ss, 16);
        ss += __shfl_xor(ss, 32);
        const float scale = 1.f / fmaxf(sqrtf(ss), 1e-12f);
        *reinterpret_cast<float2*>(&out[(es0 + e) * D_DIM + 2 * lane]) =
            make_float2(ox * scale, oy * scale);
    }
}

extern "C" void kernel_launch(void* const* d_in, const int* in_sizes, int n_in,
                              void* d_out, int out_size, void* d_ws, size_t ws_size,
                              hipStream_t stream)
{
    const int*   edge_index = (const int*)  d_in[0];   // [2,E]
    const float* edge_attr  = (const float*)d_in[1];   // [E,R]
    const int*   nbr        = (const int*)  d_in[2];   // [2,E,K]
    const float* emb        = (const float*)d_in[3];   // [N,D]
    const float* u          = (const float*)d_in[4];   // [N,R,U]
    const float* Wt         = (const float*)d_in[5];   // [R,U,A]
    const float* wt         = (const float*)d_in[6];   // [R,A]
    const float* Mt         = (const float*)d_in[7];   // [R,U,D]
    float*       out        = (float*)d_out;           // [2,E,D]

    gatne_fused<<<dim3(NBLOCKS), dim3(BLOCK), 0, stream>>>(
        edge_index, edge_attr, nbr, emb, u, Wt, wt, Mt, out);
}

// Round 3
// 654.950 us; speedup vs baseline: 1.2121x; 1.2121x over previous
//
#include <hip/hip_runtime.h>

// Problem constants (from reference)
#define E_EDGES 131072
#define K_NB    10
#define D_DIM   128
#define U_DIM   32
#define A_DIM   16
#define R_DIM   4

// Kernel tiling
#define EPG     4                    // edge-sides per wave pass
#define WAVES   16                   // waves per block (1024 threads)
#define BLOCK   (WAVES * 64)
#define NGROUPS ((2 * E_EDGES) / EPG)   // 65536 wave-groups
#define NBLOCKS (NGROUPS / WAVES)       // 4096 blocks

// fast 1/x (v_rcp_f32, ~1e-7 rel err)
__device__ __forceinline__ float frcp(float x) { return __builtin_amdgcn_rcpf(x); }

// fast tanh via hardware exp2: tanh(x) = (e^{2x}-1)/(e^{2x}+1), clamped so
// e^{2x} can't overflow (tanh saturates to 1.0f well before |x|=10)
__device__ __forceinline__ float fast_tanh(float x) {
    x = fminf(fmaxf(x, -10.f), 10.f);
    const float t = __expf(2.f * x);
    return (t - 1.f) * frcp(t + 1.f);
}

__global__ __launch_bounds__(BLOCK, 4)
void gatne_fused(const int*   __restrict__ edge_index,  // [2,E]
                 const float* __restrict__ edge_attr,   // [E,R]
                 const int*   __restrict__ nbr,         // [2,E,K]
                 const float* __restrict__ emb,         // [N,D]
                 const float* __restrict__ u,           // [N,R,U] (=[N,128])
                 const float* __restrict__ Wt,          // [R,U,A]
                 const float* __restrict__ wt,          // [R,A]
                 const float* __restrict__ Mt,          // [R,U,D] (=[128,128])
                 float*       __restrict__ out)         // [2,E,D]
{
    __shared__ float M_lds[R_DIM * U_DIM * D_DIM];      // 64 KB
    __shared__ float ur_lds[WAVES][D_DIM];              // 8 KB  (per-wave u_r)
    __shared__ float coef_lds[WAVES][EPG][D_DIM];       // 32 KB (per-wave coef)

    const int tid = threadIdx.x;

    // ---- stage M into LDS (linear copy, one barrier for the whole kernel) ----
    #pragma unroll
    for (int j = 0; j < (R_DIM * U_DIM * D_DIM) / (BLOCK * 4); ++j) {
        const int o = (j * BLOCK + tid) * 4;
        *reinterpret_cast<float4*>(&M_lds[o]) =
            *reinterpret_cast<const float4*>(&Mt[o]);
    }
    __syncthreads();

    const int wave = tid >> 6;
    const int lane = tid & 63;
    const int grp  = blockIdx.x * WAVES + wave;   // one group of EPG edge-sides
    const int es0  = grp * EPG;                   // first edge-side id
    const int side = es0 / E_EDGES;               // uniform within group
    const int i0   = es0 - side * E_EDGES;        // edge id of first

    // lane -> (r'=rl, a=al) mapping for the attention score phase
    const int rl = lane >> 4;
    const int al = lane & 15;

    // register-cache this lane's W column: W[rl, :, al]  (32 regs, constant)
    float Wreg[U_DIM];
    #pragma unroll
    for (int uu = 0; uu < U_DIM; ++uu)
        Wreg[uu] = Wt[(rl * U_DIM + uu) * A_DIM + al];
    const float wreg0 = wt[0 * A_DIM + al];
    const float wreg1 = wt[1 * A_DIM + al];
    const float wreg2 = wt[2 * A_DIM + al];
    const float wreg3 = wt[3 * A_DIM + al];

    // cooperative index / attr loads (broadcast later via shfl/readlane)
    int idxA = 0;
    if (lane < EPG * K_NB) idxA = nbr[es0 * K_NB + lane];          // 40 ints
    int entv = 0;
    if (lane < EPG)        entv = edge_index[es0 + lane];          // 4 ints
    float attrv = 0.f;
    if (lane < EPG * R_DIM) attrv = edge_attr[i0 * R_DIM + lane];  // 16 floats

    float* urp = ur_lds[wave];
    float* cfp = &coef_lds[wave][0][0];

    float2 b2[EPG];

    // ---------------- per-edge phase: gather, attention, coef ----------------
    #pragma unroll
    for (int e = 0; e < EPG; ++e) {
        const float at0 = __shfl(attrv, e * 4 + 0);
        const float at1 = __shfl(attrv, e * 4 + 1);
        const float at2 = __shfl(attrv, e * 4 + 2);
        const float at3 = __shfl(attrv, e * 4 + 3);
        const int   ent = __shfl(entv, e);
        // this lane's attr[rl] (rl == (2*lane)>>5 too, reused for coef)
        const float atm = (rl == 0) ? at0 : (rl == 1) ? at1 : (rl == 2) ? at2 : at3;

        // gather K neighbors' u rows (each lane: float2 of the 128-float row)
        float2 vals[K_NB];
        #pragma unroll
        for (int k = 0; k < K_NB; ++k) {
            const int node = __shfl(idxA, e * K_NB + k);   // uniform -> readlane
            vals[k] = *reinterpret_cast<const float2*>(&u[node * D_DIM + 2 * lane]);
        }
        b2[e] = *reinterpret_cast<const float2*>(&emb[ent * D_DIM + 2 * lane]);

        float sx = 0.f, sy = 0.f;
        #pragma unroll
        for (int k = 0; k < K_NB; ++k) { sx += vals[k].x; sy += vals[k].y; }
        sx *= 0.1f; sy *= 0.1f;                 // mean over K=10
        *reinterpret_cast<float2*>(&urp[2 * lane]) = make_float2(sx, sy);
        // wave-private LDS: in-order DS pipe makes this visible to all lanes
        // without a barrier (single-wave producer/consumer).

        // w_r[al] = sum_r' attr[r'] * w[r',al]
        const float wr = at0 * wreg0 + at1 * wreg1 + at2 * wreg2 + at3 * wreg3;

        // scores: g[r] = sum_u u_r[r,u] * W[rl,u,al];  h[r,al] = sum_rl attr*g
        float sc[R_DIM];
        #pragma unroll
        for (int r = 0; r < R_DIM; ++r) {
            float g = 0.f;
            #pragma unroll
            for (int u4 = 0; u4 < U_DIM / 4; ++u4) {
                const float4 uv =
                    *reinterpret_cast<const float4*>(&urp[r * U_DIM + u4 * 4]);
                g += uv.x * Wreg[u4 * 4 + 0];
                g += uv.y * Wreg[u4 * 4 + 1];
                g += uv.z * Wreg[u4 * 4 + 2];
                g += uv.w * Wreg[u4 * 4 + 3];
            }
            float v0 = atm * g;
            v0 += __shfl_xor(v0, 16);           // reduce over r' groups
            v0 += __shfl_xor(v0, 32);
            float t = fast_tanh(v0) * wr;       // tanh(h[r,al]) * w_r[al]
            t += __shfl_xor(t, 1);              // reduce over a
            t += __shfl_xor(t, 2);
            t += __shfl_xor(t, 4);
            t += __shfl_xor(t, 8);
            sc[r] = t;                          // score[r], replicated all lanes
        }

        // softmax over R=4 (replicated per-lane, trivial)
        const float mx  = fmaxf(fmaxf(sc[0], sc[1]), fmaxf(sc[2], sc[3]));
        const float ex0 = __expf(sc[0] - mx), ex1 = __expf(sc[1] - mx);
        const float ex2 = __expf(sc[2] - mx), ex3 = __expf(sc[3] - mx);
        const float inv = frcp(ex0 + ex1 + ex2 + ex3);
        const float a0 = ex0 * inv, a1 = ex1 * inv, a2 = ex2 * inv, a3 = ex3 * inv;

        // coef[ru] = attr[r] * v[u], v[u] = sum_r att[r]*u_r[r,u]
        // lane owns ru = 2*lane, 2*lane+1  (r = lane>>4 = rl)
        const int ub = (2 * lane) & 31;
        const float vA = a0 * urp[0 * U_DIM + ub]     + a1 * urp[1 * U_DIM + ub] +
                         a2 * urp[2 * U_DIM + ub]     + a3 * urp[3 * U_DIM + ub];
        const float vB = a0 * urp[0 * U_DIM + ub + 1] + a1 * urp[1 * U_DIM + ub + 1] +
                         a2 * urp[2 * U_DIM + ub + 1] + a3 * urp[3 * U_DIM + ub + 1];
        *reinterpret_cast<float2*>(&cfp[e * D_DIM + 2 * lane]) =
            make_float2(atm * vA, atm * vB);
    }

    // ---------------- joint matvec: out_d = sum_ru coef[ru] * M[ru,d] --------
    float2 acc[EPG];
    #pragma unroll
    for (int e = 0; e < EPG; ++e) { acc[e].x = 0.f; acc[e].y = 0.f; }

    for (int c = 0; c < (R_DIM * U_DIM) / 4; ++c) {    // 32 chunks of 4 ru
        float4 cf4[EPG];                               // uniform (broadcast) reads
        #pragma unroll
        for (int e = 0; e < EPG; ++e)
            cf4[e] = *reinterpret_cast<const float4*>(&cfp[e * D_DIM + c * 4]);
        #pragma unroll
        for (int jj = 0; jj < 4; ++jj) {
            const float2 m2 = *reinterpret_cast<const float2*>(
                &M_lds[(c * 4 + jj) * D_DIM + 2 * lane]);
            #pragma unroll
            for (int e = 0; e < EPG; ++e) {
                const float cv = (jj == 0) ? cf4[e].x : (jj == 1) ? cf4[e].y
                               : (jj == 2) ? cf4[e].z : cf4[e].w;
                acc[e].x += cv * m2.x;
                acc[e].y += cv * m2.y;
            }
        }
    }

    // ---------------- epilogue: + emb, L2 normalize, store -------------------
    #pragma unroll
    for (int e = 0; e < EPG; ++e) {
        const float ox = b2[e].x + acc[e].x;
        const float oy = b2[e].y + acc[e].y;
        float ss = ox * ox + oy * oy;
        ss += __shfl_xor(ss, 1);
        ss += __shfl_xor(ss, 2);
        ss += __shfl_xor(ss, 4);
        ss += __shfl_xor(ss, 8);
        ss += __shfl_xor(ss, 16);
        ss += __shfl_xor(ss, 32);
        const float scale = frcp(fmaxf(sqrtf(ss), 1e-12f));
        *reinterpret_cast<float2*>(&out[(es0 + e) * D_DIM + 2 * lane]) =
            make_float2(ox * scale, oy * scale);
    }
}

extern "C" void kernel_launch(void* const* d_in, const int* in_sizes, int n_in,
                              void* d_out, int out_size, void* d_ws, size_t ws_size,
                              hipStream_t stream)
{
    const int*   edge_index = (const int*)  d_in[0];   // [2,E]
    const float* edge_attr  = (const float*)d_in[1];   // [E,R]
    const int*   nbr        = (const int*)  d_in[2];   // [2,E,K]
    const float* emb        = (const float*)d_in[3];   // [N,D]
    const float* u          = (const float*)d_in[4];   // [N,R,U]
    const float* Wt         = (const float*)d_in[5];   // [R,U,A]
    const float* wt         = (const float*)d_in[6];   // [R,A]
    const float* Mt         = (const float*)d_in[7];   // [R,U,D]
    float*       out        = (float*)d_out;           // [2,E,D]

    gatne_fused<<<dim3(NBLOCKS), dim3(BLOCK), 0, stream>>>(
        edge_index, edge_attr, nbr, emb, u, Wt, wt, Mt, out);
}